// Round 9
// baseline (3533.854 us; speedup 1.0000x reference)
//
#include <hip/hip_runtime.h>
#include <math.h>

#define TT 256
#define BB 256
#define ID 512
#define HD 512
#define G4 2048            // 4*H
#define KT 1024            // IN + H
#define TBH ((size_t)TT * BB * HD)

typedef short bf16x8 __attribute__((ext_vector_type(8)));
typedef float f32x4  __attribute__((ext_vector_type(4)));
typedef unsigned short u16;
typedef u16  u16x8 __attribute__((ext_vector_type(8)));
typedef u16  u16x4 __attribute__((ext_vector_type(4)));

__device__ __forceinline__ u16 f2b(float f) {
    unsigned u = __builtin_bit_cast(unsigned, f);
    return (u16)((u + 0x7fffu + ((u >> 16) & 1u)) >> 16);   // RNE
}
__device__ __forceinline__ float b2f(u16 b) {
    unsigned u = ((unsigned)b) << 16;
    return __builtin_bit_cast(float, u);
}
__device__ __forceinline__ float sigm(float x) { return 1.f / (1.f + __expf(-x)); }
__device__ __forceinline__ float tanh_f(float x) { return 1.f - 2.f / (1.f + __expf(2.f * x)); }

// ===========================================================================
// FAST PATH (needs ~262 MB ws)
// ===========================================================================

__global__ void prep_kernel(const float* __restrict__ W_ih,
                            const float* __restrict__ W_hh,
                            const float* __restrict__ b_ih,
                            const float* __restrict__ b_hh,
                            u16* __restrict__ Wcb, float* __restrict__ bc,
                            u16* __restrict__ hb, unsigned* __restrict__ bar) {
    int idx = blockIdx.x * 256 + threadIdx.x;   // 0 .. 2M-1
    int j = idx >> 10;
    int k = idx & (KT - 1);
    float v = (k < ID) ? W_ih[(size_t)j * ID + k] : W_hh[(size_t)j * HD + (k - ID)];
    Wcb[idx] = f2b(v);
    if (idx < G4) bc[idx] = b_ih[idx] + b_hh[idx];
    if (idx < 2 * BB * HD) hb[idx] = 0;
    if (idx < 1024) bar[idx] = 0u;
}

// Xproj v2: Xp = feat @ W_ih^T + (b_ih+b_hh), bf16, MFMA D-fragment layout:
// Xp[((t*16 + mtile)*128 + ctile)*256 + lane*4 + r]
__launch_bounds__(512, 2)
__global__ void xproj_gemm(const float* __restrict__ feat,
                           const u16* __restrict__ Wcb,
                           const float* __restrict__ bc,
                           u16* __restrict__ Xp) {
    __shared__ u16 aL[65536];   // 128 KB: [f = mt*16+kk][lane][8] bf16
    const int tid = threadIdx.x;
    const int bx = blockIdx.x;
    const int t  = bx >> 3;
    const int rh = (bx >> 2) & 1;
    const int cq = bx & 3;
    const int w = tid >> 6, lane = tid & 63;
    const int l15 = lane & 15, l4 = lane >> 4;

    for (int c = tid; c < 8192; c += 512) {
        int f = c >> 6, l = c & 63;
        int mt = f >> 4, kk = f & 15;
        int row = rh * 128 + mt * 16 + (l & 15);
        int k0 = kk * 32 + (l >> 4) * 8;
        const float4* src = reinterpret_cast<const float4*>(
            feat + ((size_t)t * BB + row) * ID + k0);
        float4 v0 = src[0], v1 = src[1];
        u16x8 pk;
        pk[0]=f2b(v0.x); pk[1]=f2b(v0.y); pk[2]=f2b(v0.z); pk[3]=f2b(v0.w);
        pk[4]=f2b(v1.x); pk[5]=f2b(v1.y); pk[6]=f2b(v1.z); pk[7]=f2b(v1.w);
        *reinterpret_cast<u16x8*>(&aL[c * 8]) = pk;
    }
    __syncthreads();

    f32x4 acc[8][4] = {};
    for (int kk = 0; kk < 16; ++kk) {
        bf16x8 b[4];
        #pragma unroll
        for (int ct = 0; ct < 4; ++ct) {
            int col = cq * 512 + w * 64 + ct * 16 + l15;
            b[ct] = *reinterpret_cast<const bf16x8*>(
                Wcb + (size_t)col * KT + kk * 32 + l4 * 8);
        }
        #pragma unroll
        for (int mt = 0; mt < 8; ++mt) {
            bf16x8 a = *reinterpret_cast<const bf16x8*>(&aL[((mt * 16 + kk) * 64 + lane) * 8]);
            #pragma unroll
            for (int ct = 0; ct < 4; ++ct)
                acc[mt][ct] = __builtin_amdgcn_mfma_f32_16x16x32_bf16(a, b[ct], acc[mt][ct], 0, 0, 0);
        }
    }

    #pragma unroll
    for (int mt = 0; mt < 8; ++mt) {
        int mtile = rh * 8 + mt;
        #pragma unroll
        for (int ct = 0; ct < 4; ++ct) {
            int ctg = cq * 32 + w * 4 + ct;
            float bias = bc[ctg * 16 + l15];
            u16x4 pck;
            #pragma unroll
            for (int r = 0; r < 4; ++r) pck[r] = f2b(acc[mt][ct][r] + bias);
            *reinterpret_cast<u16x4*>(
                Xp + (((size_t)t * 16 + mtile) * 128 + ctg) * 256 + (size_t)lane * 4) = pck;
        }
    }
}

// Cooperative step kernel v6: 256 blocks x 512 thr (1 block/CU, full chip).
// Block: mb = bid&15 -> batches [mb*16,+16); nb = bid>>4 -> hcols [nb*32,+32).
// Wave (wg,wh): gate wg x hcols [wh*16,+16), 16 rows, K=512.
// Weights LDS-STATIONARY: 128 KB staged once; each wave reads a PRIVATE
// 16 KB slice per step (fragment-sequential, conflict-free, survives inv).
// Sync group = 16 blocks sharing mb (bid === mb mod 16 -> same XCD).
// R4-proven protocol: write-through publish, vmcnt drain, release add,
// relaxed poll, single acquire, outputs after signal. Final step skips sync.
__launch_bounds__(512, 2)
__global__ void lstm_coop(const int* __restrict__ mask,
                          const u16* __restrict__ Wcb,
                          const u16* __restrict__ Xp,
                          u16* hb,
                          unsigned* bar,
                          float* __restrict__ out) {
    __shared__ u16  Wl[65536];              // 128 KB: [(w*16+kk)*64+lane][8]
    __shared__ float exch[3 * 2 * 64 * 4];  // 6 KB
    const int tid = threadIdx.x;
    const int bid = blockIdx.x;
    const int mb = bid & 15;
    const int nb = bid >> 4;
    const int w = tid >> 6, lane = tid & 63;
    const int wg = w >> 1;                  // gate [0,4)
    const int wh = w & 1;                   // hcol half [0,2)
    const int l15 = lane & 15, l4 = lane >> 4;

    // ---- stage recurrent weights into LDS once (private per-wave slices) ----
    for (int c = tid; c < 8192; c += 512) {
        int wv = c >> 10;                   // target wave
        int rem = c & 1023;
        int kk = rem >> 6, l = rem & 63;
        int col = (wv >> 1) * 512 + nb * 32 + (wv & 1) * 16 + (l & 15);
        u16x8 v = *reinterpret_cast<const u16x8*>(
            Wcb + (size_t)col * KT + ID + kk * 32 + (l >> 4) * 8);
        *reinterpret_cast<u16x8*>(&Wl[c * 8]) = v;
    }
    __syncthreads();

    float* hxs0 = out;
    float* hxs1 = out + TBH;
    float* cxs  = out + 2 * TBH;

    const int hcol = nb * 32 + wh * 16 + l15;
    const int arow = mb * 16 + l15;         // A-fragment row (same for all waves)
    const u16* wls = &Wl[(w * 16 * 64) * 8];
    unsigned* bar_g = bar + mb * 64;        // group counter (256B apart)

    float c4[4] = {};                       // c-state (wg0 lanes own 4 rows)
    int p = 0;

    for (int t = 0; t < TT; ++t) {
        // own-gate input projection fragment (LLC stream, issued early)
        const int ct = wg * 32 + nb * 2 + wh;
        u16x4 xg = __builtin_nontemporal_load(reinterpret_cast<const u16x4*>(
            Xp + (((size_t)t * 16 + mb) * 128 + ct) * 256 + (size_t)lane * 4));

        // next-step keep mask (wg0 only; issued before GEMM to hide latency)
        int4 mv;
        if (wg == 0) {
            const int tm = (t + 1 < TT) ? (t + 1) : (TT - 1);
            mv = *reinterpret_cast<const int4*>(mask + tm * BB + mb * 16 + l4 * 4);
        }

        // A fragments: 16 rows x K=512 from h buffer (fresh via last acquire)
        const u16* hbp = hb + (size_t)p * BB * HD;
        bf16x8 a[16];
        #pragma unroll
        for (int kk = 0; kk < 16; ++kk)
            a[kk] = *reinterpret_cast<const bf16x8*>(
                hbp + (size_t)arow * HD + kk * 32 + l4 * 8);

        // gate GEMM: 16 MFMAs, B streamed from private LDS slice
        f32x4 acc = {};
        #pragma unroll
        for (int kk = 0; kk < 16; ++kk) {
            bf16x8 b = *reinterpret_cast<const bf16x8*>(&wls[(kk * 64 + lane) * 8]);
            acc = __builtin_amdgcn_mfma_f32_16x16x32_bf16(a[kk], b, acc, 0, 0, 0);
        }
        #pragma unroll
        for (int r = 0; r < 4; ++r) acc[r] += b2f(xg[r]);

        // hand gates 1..3 to the pointwise owner (wg0)
        if (wg >= 1)
            *reinterpret_cast<f32x4*>(&exch[(((wg - 1) * 2 + wh) * 64 + lane) * 4]) = acc;
        __syncthreads();

        float hv[4], cv[4];
        u16* hbn = hb + (size_t)(p ^ 1) * BB * HD;
        if (wg == 0) {
            f32x4 pf = *reinterpret_cast<const f32x4*>(&exch[((0 * 2 + wh) * 64 + lane) * 4]);
            f32x4 pg = *reinterpret_cast<const f32x4*>(&exch[((1 * 2 + wh) * 64 + lane) * 4]);
            f32x4 po = *reinterpret_cast<const f32x4*>(&exch[((2 * 2 + wh) * 64 + lane) * 4]);
            #pragma unroll
            for (int r = 0; r < 4; ++r) {
                float kni = 1.f - (float)((&mv.x)[r]);
                float ig = sigm(acc[r]);
                float fg = sigm(pf[r]);
                float gc = tanh_f(pg[r]);
                float og = sigm(po[r]);
                float c = fg * c4[r] + ig * gc;     // c4 pre-scaled by keep
                float h = og * tanh_f(c);
                hv[r] = h; cv[r] = c;
                c4[r] = c * kni;

                // publish next-h (bf16, masked): packed write-through atomics
                if (t + 1 < TT) {
                    unsigned mine = (unsigned)f2b(h * kni);
                    unsigned oth  = (unsigned)__shfl_xor((int)mine, 1, 64);
                    if (!(lane & 1)) {
                        unsigned pk = (mine & 0xffffu) | (oth << 16);
                        __hip_atomic_store(
                            reinterpret_cast<unsigned*>(
                                hbn + (size_t)(mb * 16 + l4 * 4 + r) * HD + hcol),
                            pk, __ATOMIC_RELAXED, __HIP_MEMORY_SCOPE_AGENT);
                    }
                }
            }
        }

        if (t + 1 < TT) {
            // drain publishes, then signal
            asm volatile("s_waitcnt vmcnt(0)" ::: "memory");
            __syncthreads();
            if (tid == 0)
                __hip_atomic_fetch_add(bar_g, 1u, __ATOMIC_RELEASE, __HIP_MEMORY_SCOPE_AGENT);

            // output stores drain during the poll (off critical path)
            if (wg == 0) {
                #pragma unroll
                for (int r = 0; r < 4; ++r) {
                    size_t o = ((size_t)t * BB + (mb * 16 + l4 * 4 + r)) * HD + hcol;
                    __builtin_nontemporal_store(hv[r], hxs0 + o);
                    __builtin_nontemporal_store(hv[r], hxs1 + o);
                    __builtin_nontemporal_store(cv[r], cxs + o);
                }
            }

            if (tid == 0) {
                unsigned target = (unsigned)(t + 1) * 16u;
                while (__hip_atomic_load(bar_g, __ATOMIC_RELAXED, __HIP_MEMORY_SCOPE_AGENT) < target)
                    __builtin_amdgcn_s_sleep(1);
                (void)__hip_atomic_load(bar_g, __ATOMIC_ACQUIRE, __HIP_MEMORY_SCOPE_AGENT);
            }
            __syncthreads();
        } else {
            // final step: no publish/sync, just outputs
            if (wg == 0) {
                #pragma unroll
                for (int r = 0; r < 4; ++r) {
                    size_t o = ((size_t)t * BB + (mb * 16 + l4 * 4 + r)) * HD + hcol;
                    __builtin_nontemporal_store(hv[r], hxs0 + o);
                    __builtin_nontemporal_store(hv[r], hxs1 + o);
                    __builtin_nontemporal_store(cv[r], cxs + o);
                }
            }
        }
        p ^= 1;
    }
}

// ===========================================================================
// FALLBACK PATH (round-1, validated): per-step launches, fp32 VALU
// ===========================================================================
__global__ void prep_r1(const float* __restrict__ W_ih, const float* __restrict__ W_hh,
                        const float* __restrict__ b_ih, const float* __restrict__ b_hh,
                        float* __restrict__ WcT, float* __restrict__ bc) {
    int idx = blockIdx.x * 256 + threadIdx.x;
    int k = idx >> 11;
    int j = idx & (G4 - 1);
    float v = (k < ID) ? W_ih[(size_t)j * ID + k] : W_hh[(size_t)j * HD + (k - ID)];
    WcT[idx] = v;
    if (idx < G4) bc[idx] = b_ih[idx] + b_hh[idx];
}

__launch_bounds__(512, 2)
__global__ void lstm_step_r1(int t, int use_ws,
                             const float* __restrict__ feat, const int* __restrict__ mask,
                             const float* __restrict__ W_ih, const float* __restrict__ W_hh,
                             const float* __restrict__ b_ih, const float* __restrict__ b_hh,
                             const float* __restrict__ WcT, const float* __restrict__ bc,
                             float* __restrict__ out) {
    __shared__ float4 xh4[16][256];
    const int tid = threadIdx.x;
    const int c0 = blockIdx.x * 32;
    const int b0 = blockIdx.y * 16;
    float* hxs0 = out;
    float* hxs1 = out + TBH;
    float* cxs  = out + 2 * TBH;

    for (int e = tid; e < 16 * 256; e += 512) {
        int bl = e >> 8, q = e & 255, b = b0 + bl;
        float4 v;
        if (q < 128) {
            v = reinterpret_cast<const float4*>(feat + ((size_t)t * BB + b) * ID)[q];
        } else if (t == 0) {
            v = make_float4(0.f, 0.f, 0.f, 0.f);
        } else {
            float keep = 1.0f - (float)mask[t * BB + b];
            v = reinterpret_cast<const float4*>(hxs0 + ((size_t)(t - 1) * BB + b) * HD)[q - 128];
            v.x *= keep; v.y *= keep; v.z *= keep; v.w *= keep;
        }
        xh4[bl][q] = v;
    }
    __syncthreads();

    const int lc = tid & 127, bh = tid >> 7;
    const int j = (lc >> 5) * HD + c0 + (lc & 31);
    float acc[4] = {0.f, 0.f, 0.f, 0.f};
    if (use_ws) {
        for (int k = 0; k < KT; k += 4) {
            float w0 = WcT[(size_t)(k + 0) * G4 + j];
            float w1 = WcT[(size_t)(k + 1) * G4 + j];
            float w2 = WcT[(size_t)(k + 2) * G4 + j];
            float w3 = WcT[(size_t)(k + 3) * G4 + j];
            #pragma unroll
            for (int i = 0; i < 4; ++i) {
                float4 x = xh4[bh * 4 + i][k >> 2];
                acc[i] = fmaf(x.x, w0, acc[i]); acc[i] = fmaf(x.y, w1, acc[i]);
                acc[i] = fmaf(x.z, w2, acc[i]); acc[i] = fmaf(x.w, w3, acc[i]);
            }
        }
    } else {
        const float4* wi = reinterpret_cast<const float4*>(W_ih + (size_t)j * ID);
        const float4* wh = reinterpret_cast<const float4*>(W_hh + (size_t)j * HD);
        for (int k = 0; k < KT; k += 4) {
            float4 wv = (k < ID) ? wi[k >> 2] : wh[(k - ID) >> 2];
            #pragma unroll
            for (int i = 0; i < 4; ++i) {
                float4 x = xh4[bh * 4 + i][k >> 2];
                acc[i] = fmaf(x.x, wv.x, acc[i]); acc[i] = fmaf(x.y, wv.y, acc[i]);
                acc[i] = fmaf(x.z, wv.z, acc[i]); acc[i] = fmaf(x.w, wv.w, acc[i]);
            }
        }
    }
    float gbias = use_ws ? bc[j] : (b_ih[j] + b_hh[j]);
    __syncthreads();
    float* gbuf = reinterpret_cast<float*>(xh4);
    #pragma unroll
    for (int i = 0; i < 4; ++i) gbuf[lc * 16 + bh * 4 + i] = acc[i] + gbias;
    __syncthreads();
    {
        int hc = tid & 31, bl = tid >> 5, b = b0 + bl;
        float keep = 1.0f - (float)mask[t * BB + b];
        float cp = 0.f;
        if (t > 0) cp = cxs[((size_t)(t - 1) * BB + b) * HD + c0 + hc];
        cp *= keep;
        float ig = gbuf[(0 * 32 + hc) * 16 + bl];
        float fg = gbuf[(1 * 32 + hc) * 16 + bl];
        float gg = gbuf[(2 * 32 + hc) * 16 + bl];
        float og = gbuf[(3 * 32 + hc) * 16 + bl];
        ig = 1.0f / (1.0f + __expf(-ig));
        fg = 1.0f / (1.0f + __expf(-fg));
        gg = tanhf(gg);
        og = 1.0f / (1.0f + __expf(-og));
        float cn = fg * cp + ig * gg;
        float hn = og * tanhf(cn);
        size_t o = ((size_t)t * BB + b) * HD + c0 + hc;
        hxs0[o] = hn; hxs1[o] = hn; cxs[o] = cn;
    }
}

// ===========================================================================
extern "C" void kernel_launch(void* const* d_in, const int* in_sizes, int n_in,
                              void* d_out, int out_size, void* d_ws, size_t ws_size,
                              hipStream_t stream) {
    const float* feat = (const float*)d_in[0];
    const int*   mask = (const int*)d_in[1];
    const float* W_ih = (const float*)d_in[2];
    const float* W_hh = (const float*)d_in[3];
    const float* b_ih = (const float*)d_in[4];
    const float* b_hh = (const float*)d_in[5];
    float* out = (float*)d_out;

    size_t offWcb = 0;
    size_t offBc  = offWcb + (size_t)G4 * KT * sizeof(u16);          // 4 MB
    size_t offHb  = offBc  + (size_t)G4 * sizeof(float);             // +8 KB
    size_t offBar = offHb  + (size_t)2 * BB * HD * sizeof(u16);      // +512 KB
    size_t offXp  = (offBar + 4096 + 255) & ~(size_t)255;            // +4 KB
    size_t need   = offXp + (size_t)TT * BB * G4 * sizeof(u16);      // +268.4 MB

    if (d_ws != nullptr && ws_size >= need) {
        char* ws = (char*)d_ws;
        u16*      Wcb = (u16*)(ws + offWcb);
        float*    bc  = (float*)(ws + offBc);
        u16*      hb  = (u16*)(ws + offHb);
        unsigned* bar = (unsigned*)(ws + offBar);
        u16*      Xp  = (u16*)(ws + offXp);

        prep_kernel<<<(G4 * KT) / 256, 256, 0, stream>>>(W_ih, W_hh, b_ih, b_hh, Wcb, bc, hb, bar);
        xproj_gemm<<<2048, 512, 0, stream>>>(feat, Wcb, bc, Xp);
        lstm_coop<<<256, 512, 0, stream>>>(mask, Wcb, Xp, hb, bar, out);
    } else {
        float* WcT = (float*)d_ws;
        float* bcf = WcT + (size_t)KT * G4;
        const size_t ws_needed = ((size_t)KT * G4 + G4) * sizeof(float);
        int use_ws = (d_ws != nullptr && ws_size >= ws_needed) ? 1 : 0;
        if (use_ws)
            prep_r1<<<(KT * G4) / 256, 256, 0, stream>>>(W_ih, W_hh, b_ih, b_hh, WcT, bcf);
        dim3 grid(16, 16);
        for (int t = 0; t < TT; ++t)
            lstm_step_r1<<<grid, 512, 0, stream>>>(t, use_ws, feat, mask,
                                                   W_ih, W_hh, b_ih, b_hh, WcT, bcf, out);
    }
}

// Round 10
// 2306.541 us; speedup vs baseline: 1.5321x; 1.5321x over previous
//
#include <hip/hip_runtime.h>
#include <math.h>

#define TT 256
#define BB 256
#define ID 512
#define HD 512
#define G4 2048            // 4*H
#define KT 1024            // IN + H
#define TBH ((size_t)TT * BB * HD)

typedef short bf16x8 __attribute__((ext_vector_type(8)));
typedef float f32x4  __attribute__((ext_vector_type(4)));
typedef unsigned short u16;
typedef u16  u16x8 __attribute__((ext_vector_type(8)));
typedef u16  u16x4 __attribute__((ext_vector_type(4)));

__device__ __forceinline__ u16 f2b(float f) {
    unsigned u = __builtin_bit_cast(unsigned, f);
    return (u16)((u + 0x7fffu + ((u >> 16) & 1u)) >> 16);   // RNE
}
__device__ __forceinline__ float b2f(u16 b) {
    unsigned u = ((unsigned)b) << 16;
    return __builtin_bit_cast(float, u);
}
__device__ __forceinline__ float sigm(float x) { return 1.f / (1.f + __expf(-x)); }
__device__ __forceinline__ float tanh_f(float x) { return 1.f - 2.f / (1.f + __expf(2.f * x)); }

// ===========================================================================
// FAST PATH (needs ~263 MB ws)
// ===========================================================================

// Prep: Wcb[col][k] bf16 (for xproj), bc = b_ih+b_hh,
// Wfrag = recurrent weights repacked fragment-sequential for the step kernel:
//   Wfrag[(((nb*8 + w)*16 + kk)*64 + lane)*8 + j]
//   where w = wg*2+wh, col = wg*512 + nb*32 + wh*16 + (lane&15),
//         k = kk*32 + (lane>>4)*8 + j   (recurrent k, 0..511)
__global__ void prep_kernel(const float* __restrict__ W_ih,
                            const float* __restrict__ W_hh,
                            const float* __restrict__ b_ih,
                            const float* __restrict__ b_hh,
                            u16* __restrict__ Wcb, float* __restrict__ bc,
                            u16* __restrict__ Wfrag) {
    int idx = blockIdx.x * 256 + threadIdx.x;   // 0 .. 2M-1
    int j = idx >> 10;
    int k = idx & (KT - 1);
    float v = (k < ID) ? W_ih[(size_t)j * ID + k] : W_hh[(size_t)j * HD + (k - ID)];
    Wcb[idx] = f2b(v);
    if (idx < G4) bc[idx] = b_ih[idx] + b_hh[idx];

    if (idx < 16 * 8 * 16 * 64) {               // 131072 16B chunks
        int nb = idx >> 13;
        int w  = (idx >> 10) & 7;
        int kk = (idx >> 6) & 15;
        int l  = idx & 63;
        int wg = w >> 1, wh = w & 1;
        int col = wg * 512 + nb * 32 + wh * 16 + (l & 15);
        int k0  = kk * 32 + (l >> 4) * 8;
        const float* src = W_hh + (size_t)col * HD + k0;
        u16x8 pk;
        #pragma unroll
        for (int e = 0; e < 8; ++e) pk[e] = f2b(src[e]);
        *reinterpret_cast<u16x8*>(Wfrag + (size_t)idx * 8) = pk;
    }
}

// Xproj v2: Xp = feat @ W_ih^T + (b_ih+b_hh), bf16, MFMA D-fragment layout:
// Xp[((t*16 + mtile)*128 + ctile)*256 + lane*4 + r]
__launch_bounds__(512, 2)
__global__ void xproj_gemm(const float* __restrict__ feat,
                           const u16* __restrict__ Wcb,
                           const float* __restrict__ bc,
                           u16* __restrict__ Xp) {
    __shared__ u16 aL[65536];   // 128 KB: [f = mt*16+kk][lane][8] bf16
    const int tid = threadIdx.x;
    const int bx = blockIdx.x;
    const int t  = bx >> 3;
    const int rh = (bx >> 2) & 1;
    const int cq = bx & 3;
    const int w = tid >> 6, lane = tid & 63;
    const int l15 = lane & 15, l4 = lane >> 4;

    for (int c = tid; c < 8192; c += 512) {
        int f = c >> 6, l = c & 63;
        int mt = f >> 4, kk = f & 15;
        int row = rh * 128 + mt * 16 + (l & 15);
        int k0 = kk * 32 + (l >> 4) * 8;
        const float4* src = reinterpret_cast<const float4*>(
            feat + ((size_t)t * BB + row) * ID + k0);
        float4 v0 = src[0], v1 = src[1];
        u16x8 pk;
        pk[0]=f2b(v0.x); pk[1]=f2b(v0.y); pk[2]=f2b(v0.z); pk[3]=f2b(v0.w);
        pk[4]=f2b(v1.x); pk[5]=f2b(v1.y); pk[6]=f2b(v1.z); pk[7]=f2b(v1.w);
        *reinterpret_cast<u16x8*>(&aL[c * 8]) = pk;
    }
    __syncthreads();

    f32x4 acc[8][4] = {};
    for (int kk = 0; kk < 16; ++kk) {
        bf16x8 b[4];
        #pragma unroll
        for (int ct = 0; ct < 4; ++ct) {
            int col = cq * 512 + w * 64 + ct * 16 + l15;
            b[ct] = *reinterpret_cast<const bf16x8*>(
                Wcb + (size_t)col * KT + kk * 32 + l4 * 8);
        }
        #pragma unroll
        for (int mt = 0; mt < 8; ++mt) {
            bf16x8 a = *reinterpret_cast<const bf16x8*>(&aL[((mt * 16 + kk) * 64 + lane) * 8]);
            #pragma unroll
            for (int ct = 0; ct < 4; ++ct)
                acc[mt][ct] = __builtin_amdgcn_mfma_f32_16x16x32_bf16(a, b[ct], acc[mt][ct], 0, 0, 0);
        }
    }

    #pragma unroll
    for (int mt = 0; mt < 8; ++mt) {
        int mtile = rh * 8 + mt;
        #pragma unroll
        for (int ct = 0; ct < 4; ++ct) {
            int ctg = cq * 32 + w * 4 + ct;
            float bias = bc[ctg * 16 + l15];
            u16x4 pck;
            #pragma unroll
            for (int r = 0; r < 4; ++r) pck[r] = f2b(acc[mt][ct][r] + bias);
            *reinterpret_cast<u16x4*>(
                Xp + (((size_t)t * 16 + mtile) * 128 + ctg) * 256 + (size_t)lane * 4) = pck;
        }
    }
}

// Per-step kernel v10: one launch per time step; the kernel boundary IS the
// sync (no atomics, no acquire-inv, L2 stays warm). 256 blocks x 512 thr.
// Block: mb = bid&15 -> batches [mb*16,+16); nb = bid>>4 -> hcols [nb*32,+32).
// Wave (wg,wh): gate wg x hcols [wh*16,+16). 16 MFMAs/wave.
// State: hb (bf16, pre-masked, double-buffered) + cb (f32, pre-masked) in ws.
// t==0 reads NO state (replay-safe without re-zeroing).
__launch_bounds__(512, 2)
__global__ void lstm_step(int t,
                          const int* __restrict__ mask,
                          const u16* __restrict__ Wfrag,
                          const u16* __restrict__ Xp,
                          const u16* __restrict__ hbp,
                          u16* __restrict__ hbn,
                          float* __restrict__ cb,
                          float* __restrict__ out) {
    __shared__ float exch[3 * 2 * 64 * 4];  // 6 KB
    const int tid = threadIdx.x;
    const int bid = blockIdx.x;
    const int mb = bid & 15;
    const int nb = bid >> 4;
    const int w = tid >> 6, lane = tid & 63;
    const int wg = w >> 1;                  // gate [0,4)
    const int wh = w & 1;                   // hcol half [0,2)
    const int l15 = lane & 15, l4 = lane >> 4;

    float* hxs0 = out;
    float* hxs1 = out + TBH;
    float* cxs  = out + 2 * TBH;

    const int hcol = nb * 32 + wh * 16 + l15;
    const int arow = mb * 16 + l15;

    // input-projection fragment (own gate)
    const int ct = wg * 32 + nb * 2 + wh;
    u16x4 xg = *reinterpret_cast<const u16x4*>(
        Xp + (((size_t)t * 16 + mb) * 128 + ct) * 256 + (size_t)lane * 4);

    // recurrent GEMM: 16 MFMAs, A from h state, B from coalesced Wfrag (L2-warm)
    f32x4 acc = {};
    if (t > 0) {
        const u16* wb = Wfrag + (size_t)(nb * 8 + w) * 16 * 64 * 8;
        #pragma unroll
        for (int kk = 0; kk < 16; ++kk) {
            bf16x8 a = *reinterpret_cast<const bf16x8*>(
                hbp + (size_t)arow * HD + kk * 32 + l4 * 8);
            bf16x8 b = *reinterpret_cast<const bf16x8*>(wb + (kk * 64 + lane) * 8);
            acc = __builtin_amdgcn_mfma_f32_16x16x32_bf16(a, b, acc, 0, 0, 0);
        }
    }
    #pragma unroll
    for (int r = 0; r < 4; ++r) acc[r] += b2f(xg[r]);

    // hand gates 1..3 to the pointwise owner (wg0)
    if (wg >= 1)
        *reinterpret_cast<f32x4*>(&exch[(((wg - 1) * 2 + wh) * 64 + lane) * 4]) = acc;
    __syncthreads();

    if (wg == 0) {
        f32x4 pf = *reinterpret_cast<const f32x4*>(&exch[((0 * 2 + wh) * 64 + lane) * 4]);
        f32x4 pg = *reinterpret_cast<const f32x4*>(&exch[((1 * 2 + wh) * 64 + lane) * 4]);
        f32x4 po = *reinterpret_cast<const f32x4*>(&exch[((2 * 2 + wh) * 64 + lane) * 4]);
        const int tm = (t + 1 < TT) ? (t + 1) : (TT - 1);
        int4 mv = *reinterpret_cast<const int4*>(mask + tm * BB + mb * 16 + l4 * 4);
        #pragma unroll
        for (int r = 0; r < 4; ++r) {
            const int row = mb * 16 + l4 * 4 + r;
            float cprev = (t > 0) ? cb[(size_t)row * HD + hcol] : 0.f;  // pre-masked
            float kni = 1.f - (float)((&mv.x)[r]);
            float ig = sigm(acc[r]);
            float fg = sigm(pf[r]);
            float gc = tanh_f(pg[r]);
            float og = sigm(po[r]);
            float c = fg * cprev + ig * gc;
            float h = og * tanh_f(c);

            cb[(size_t)row * HD + hcol] = c * kni;          // pre-masked c-state

            // pre-masked h-state (bf16), packed pairwise for 4B stores
            unsigned mine = (unsigned)f2b(h * kni);
            unsigned oth  = (unsigned)__shfl_xor((int)mine, 1, 64);
            if (!(lane & 1)) {
                unsigned pk = (mine & 0xffffu) | (oth << 16);
                *reinterpret_cast<unsigned*>(hbn + (size_t)row * HD + hcol) = pk;
            }

            // outputs
            size_t o = ((size_t)t * BB + row) * HD + hcol;
            __builtin_nontemporal_store(h, hxs0 + o);
            __builtin_nontemporal_store(h, hxs1 + o);
            __builtin_nontemporal_store(c, cxs + o);
        }
    }
}

// ===========================================================================
// FALLBACK PATH (round-1, validated): per-step launches, fp32 VALU
// ===========================================================================
__global__ void prep_r1(const float* __restrict__ W_ih, const float* __restrict__ W_hh,
                        const float* __restrict__ b_ih, const float* __restrict__ b_hh,
                        float* __restrict__ WcT, float* __restrict__ bc) {
    int idx = blockIdx.x * 256 + threadIdx.x;
    int k = idx >> 11;
    int j = idx & (G4 - 1);
    float v = (k < ID) ? W_ih[(size_t)j * ID + k] : W_hh[(size_t)j * HD + (k - ID)];
    WcT[idx] = v;
    if (idx < G4) bc[idx] = b_ih[idx] + b_hh[idx];
}

__launch_bounds__(512, 2)
__global__ void lstm_step_r1(int t, int use_ws,
                             const float* __restrict__ feat, const int* __restrict__ mask,
                             const float* __restrict__ W_ih, const float* __restrict__ W_hh,
                             const float* __restrict__ b_ih, const float* __restrict__ b_hh,
                             const float* __restrict__ WcT, const float* __restrict__ bc,
                             float* __restrict__ out) {
    __shared__ float4 xh4[16][256];
    const int tid = threadIdx.x;
    const int c0 = blockIdx.x * 32;
    const int b0 = blockIdx.y * 16;
    float* hxs0 = out;
    float* hxs1 = out + TBH;
    float* cxs  = out + 2 * TBH;

    for (int e = tid; e < 16 * 256; e += 512) {
        int bl = e >> 8, q = e & 255, b = b0 + bl;
        float4 v;
        if (q < 128) {
            v = reinterpret_cast<const float4*>(feat + ((size_t)t * BB + b) * ID)[q];
        } else if (t == 0) {
            v = make_float4(0.f, 0.f, 0.f, 0.f);
        } else {
            float keep = 1.0f - (float)mask[t * BB + b];
            v = reinterpret_cast<const float4*>(hxs0 + ((size_t)(t - 1) * BB + b) * HD)[q - 128];
            v.x *= keep; v.y *= keep; v.z *= keep; v.w *= keep;
        }
        xh4[bl][q] = v;
    }
    __syncthreads();

    const int lc = tid & 127, bh = tid >> 7;
    const int j = (lc >> 5) * HD + c0 + (lc & 31);
    float acc[4] = {0.f, 0.f, 0.f, 0.f};
    if (use_ws) {
        for (int k = 0; k < KT; k += 4) {
            float w0 = WcT[(size_t)(k + 0) * G4 + j];
            float w1 = WcT[(size_t)(k + 1) * G4 + j];
            float w2 = WcT[(size_t)(k + 2) * G4 + j];
            float w3 = WcT[(size_t)(k + 3) * G4 + j];
            #pragma unroll
            for (int i = 0; i < 4; ++i) {
                float4 x = xh4[bh * 4 + i][k >> 2];
                acc[i] = fmaf(x.x, w0, acc[i]); acc[i] = fmaf(x.y, w1, acc[i]);
                acc[i] = fmaf(x.z, w2, acc[i]); acc[i] = fmaf(x.w, w3, acc[i]);
            }
        }
    } else {
        const float4* wi = reinterpret_cast<const float4*>(W_ih + (size_t)j * ID);
        const float4* wh = reinterpret_cast<const float4*>(W_hh + (size_t)j * HD);
        for (int k = 0; k < KT; k += 4) {
            float4 wv = (k < ID) ? wi[k >> 2] : wh[(k - ID) >> 2];
            #pragma unroll
            for (int i = 0; i < 4; ++i) {
                float4 x = xh4[bh * 4 + i][k >> 2];
                acc[i] = fmaf(x.x, wv.x, acc[i]); acc[i] = fmaf(x.y, wv.y, acc[i]);
                acc[i] = fmaf(x.z, wv.z, acc[i]); acc[i] = fmaf(x.w, wv.w, acc[i]);
            }
        }
    }
    float gbias = use_ws ? bc[j] : (b_ih[j] + b_hh[j]);
    __syncthreads();
    float* gbuf = reinterpret_cast<float*>(xh4);
    #pragma unroll
    for (int i = 0; i < 4; ++i) gbuf[lc * 16 + bh * 4 + i] = acc[i] + gbias;
    __syncthreads();
    {
        int hc = tid & 31, bl = tid >> 5, b = b0 + bl;
        float keep = 1.0f - (float)mask[t * BB + b];
        float cp = 0.f;
        if (t > 0) cp = cxs[((size_t)(t - 1) * BB + b) * HD + c0 + hc];
        cp *= keep;
        float ig = gbuf[(0 * 32 + hc) * 16 + bl];
        float fg = gbuf[(1 * 32 + hc) * 16 + bl];
        float gg = gbuf[(2 * 32 + hc) * 16 + bl];
        float og = gbuf[(3 * 32 + hc) * 16 + bl];
        ig = 1.0f / (1.0f + __expf(-ig));
        fg = 1.0f / (1.0f + __expf(-fg));
        gg = tanhf(gg);
        og = 1.0f / (1.0f + __expf(-og));
        float cn = fg * cp + ig * gg;
        float hn = og * tanhf(cn);
        size_t o = ((size_t)t * BB + b) * HD + c0 + hc;
        hxs0[o] = hn; hxs1[o] = hn; cxs[o] = cn;
    }
}

// ===========================================================================
extern "C" void kernel_launch(void* const* d_in, const int* in_sizes, int n_in,
                              void* d_out, int out_size, void* d_ws, size_t ws_size,
                              hipStream_t stream) {
    const float* feat = (const float*)d_in[0];
    const int*   mask = (const int*)d_in[1];
    const float* W_ih = (const float*)d_in[2];
    const float* W_hh = (const float*)d_in[3];
    const float* b_ih = (const float*)d_in[4];
    const float* b_hh = (const float*)d_in[5];
    float* out = (float*)d_out;

    size_t offWcb   = 0;
    size_t offBc    = offWcb   + (size_t)G4 * KT * sizeof(u16);        // 4 MB
    size_t offWfrag = offBc    + (size_t)G4 * sizeof(float);           // +8 KB
    size_t offHb    = offWfrag + (size_t)G4 * ID * sizeof(u16);        // +2 MB
    size_t offCb    = offHb    + (size_t)2 * BB * HD * sizeof(u16);    // +512 KB
    size_t offXp    = (offCb   + (size_t)BB * HD * sizeof(float) + 255) & ~(size_t)255; // +512 KB
    size_t need     = offXp    + (size_t)TT * BB * G4 * sizeof(u16);   // +256 MB

    if (d_ws != nullptr && ws_size >= need) {
        char* ws = (char*)d_ws;
        u16*   Wcb   = (u16*)(ws + offWcb);
        float* bc    = (float*)(ws + offBc);
        u16*   Wfrag = (u16*)(ws + offWfrag);
        u16*   hb    = (u16*)(ws + offHb);
        float* cb    = (float*)(ws + offCb);
        u16*   Xp    = (u16*)(ws + offXp);

        prep_kernel<<<(G4 * KT) / 256, 256, 0, stream>>>(W_ih, W_hh, b_ih, b_hh, Wcb, bc, Wfrag);
        xproj_gemm<<<2048, 512, 0, stream>>>(feat, Wcb, bc, Xp);
        for (int t = 0; t < TT; ++t) {
            const u16* hbp = hb + (size_t)(t & 1) * BB * HD;
            u16*       hbn = hb + (size_t)((t + 1) & 1) * BB * HD;
            lstm_step<<<256, 512, 0, stream>>>(t, mask, Wfrag, Xp, hbp, hbn, cb, out);
        }
    } else {
        float* WcT = (float*)d_ws;
        float* bcf = WcT + (size_t)KT * G4;
        const size_t ws_needed = ((size_t)KT * G4 + G4) * sizeof(float);
        int use_ws = (d_ws != nullptr && ws_size >= ws_needed) ? 1 : 0;
        if (use_ws)
            prep_r1<<<(KT * G4) / 256, 256, 0, stream>>>(W_ih, W_hh, b_ih, b_hh, WcT, bcf);
        dim3 grid(16, 16);
        for (int t = 0; t < TT; ++t)
            lstm_step_r1<<<grid, 512, 0, stream>>>(t, use_ws, feat, mask,
                                                   W_ih, W_hh, b_ih, b_hh, WcT, bcf, out);
    }
}